// Round 3
// baseline (73.453 us; speedup 1.0000x reference)
//
#include <hip/hip_runtime.h>
#include <math.h>

#define RR 16
#define AA 8
#define BLOCK 256

// ws float layout (param rows permuted into c1-sorted order "k"):
//   [0..127]    mP   : m[k][a]   for rule p1[k]
//   [128..255]  ibP  : 1/sigma_big   (bigger sigma  -> UU / mu_big)
//   [256..383]  isP  : 1/sigma_small (smaller sigma -> LL / mu_small)
//   [384..399]  c1s  : c1 sorted ascending
//   [400..415]  c2p  : c2[p1[k]]  (c2 coeffs in p1 order, for s0r/t0r sums)
//   [416..431]  c2s  : c2 sorted ascending
//   [432..447]  qI   : (int) position in p1-order of rule p2[k]

__global__ void prep_kernel(const float* __restrict__ W,
                            const float* __restrict__ c1,
                            const float* __restrict__ c2,
                            float* __restrict__ ws) {
    int t = threadIdx.x;   // 64 threads, 1 block; 0..15 active
    if (t >= RR) return;

    float v1 = c1[t];
    int r1 = 0;                         // stable rank in c1 (== inv p1 of rule t)
    #pragma unroll
    for (int j = 0; j < RR; ++j) {
        float vj = c1[j];
        r1 += (vj < v1) || (vj == v1 && j < t);
    }
    float v2 = c2[t];
    int r2 = 0;                         // stable rank in c2
    #pragma unroll
    for (int j = 0; j < RR; ++j) {
        float vj = c2[j];
        r2 += (vj < v2) || (vj == v2 && j < t);
    }

    // write rule t's params into sorted row r1
    #pragma unroll
    for (int a = 0; a < AA; ++a) {
        int o = t * AA + a;             // offsets = 8r + a ; m=W[o], s1=W[o+1], s2=W[o+2]
        float m  = W[o];
        float s1 = W[o + 1];
        float s2 = W[o + 2];
        ws[r1 * AA + a]        = m;
        ws[128 + r1 * AA + a]  = 1.0f / fmaxf(s1, s2);
        ws[256 + r1 * AA + a]  = 1.0f / fminf(s1, s2);
    }
    ws[384 + r1] = v1;
    ws[400 + r1] = v2;                  // c2 coefficient of the rule at p1-position r1
    ws[416 + r2] = v2;                  // sorted c2
    ((int*)ws)[432 + r2] = r1;          // q[k] = where rule p2[k] sits in p1 order
}

__device__ __forceinline__ void acc4(const float4 xv, const float4 m,
                                     const float4 ib, const float4 is,
                                     float& ab, float& as) {
    float t;
    t = xv.x - m.x; ab = fmaf(t * ib.x, t * ib.x, ab); as = fmaf(t * is.x, t * is.x, as);
    t = xv.y - m.y; ab = fmaf(t * ib.y, t * ib.y, ab); as = fmaf(t * is.y, t * is.y, as);
    t = xv.z - m.z; ab = fmaf(t * ib.z, t * ib.z, ab); as = fmaf(t * is.z, t * is.z, as);
    t = xv.w - m.w; ab = fmaf(t * ib.w, t * ib.w, ab); as = fmaf(t * is.w, t * is.w, as);
}

__global__ __launch_bounds__(BLOCK) void t2fls_main(
    const float* __restrict__ x,    // N x 8
    const float* __restrict__ ws,   // prepped uniforms
    float* __restrict__ out,        // N
    int n)
{
    __shared__ float2 UL[RR][BLOCK];    // 32 KiB; own-column access, no barrier

    const int tid = threadIdx.x;
    const int gid = blockIdx.x * BLOCK + tid;
    if (gid >= n) return;

    const float4* xp = (const float4*)(x + (size_t)gid * AA);
    const float4 xA = xp[0], xB = xp[1];

    const float4* mP4 = (const float4*)(ws);
    const float4* ib4 = (const float4*)(ws + 128);
    const float4* is4 = (const float4*)(ws + 256);

    // ---- firing: per-rule d^2 sums, already in c1-sorted order ----
    float sb[RR], ss[RR];
    #pragma unroll
    for (int k = 0; k < RR; ++k) {
        float ab = 0.0f, as = 0.0f;
        acc4(xA, mP4[2 * k],     ib4[2 * k],     is4[2 * k],     ab, as);
        acc4(xB, mP4[2 * k + 1], ib4[2 * k + 1], is4[2 * k + 1], ab, as);
        sb[k] = ab;
        ss[k] = as;
    }

    // ---- exact pow2 relative rescale (KM ratios are scale-invariant) ----
    float smin = sb[0];
    #pragma unroll
    for (int k = 1; k < RR; ++k) smin = fminf(smin, sb[k]);

    const float K = 0.72134752044448f;  // 0.5 * log2(e)
    float u[RR], l[RR];
    #pragma unroll
    for (int k = 0; k < RR; ++k) {
        u[k] = __builtin_amdgcn_exp2f((smin - sb[k]) * K);   // scaled UU, max = 1
        l[k] = __builtin_amdgcn_exp2f((smin - ss[k]) * K);   // scaled LL <= u
    }

    // ---- coefficient vectors (float4 loads, stay uniform) ----
    float c1s[RR], c2p[RR], c2s[RR];
    int   q[RR];
    {
        const float4* a4 = (const float4*)(ws + 384);
        const float4* b4 = (const float4*)(ws + 400);
        const float4* c4 = (const float4*)(ws + 416);
        const int4*   q4 = (const int4*)((const int*)ws + 432);
        #pragma unroll
        for (int i = 0; i < 4; ++i) {
            float4 a = a4[i]; c1s[4*i] = a.x; c1s[4*i+1] = a.y; c1s[4*i+2] = a.z; c1s[4*i+3] = a.w;
            float4 b = b4[i]; c2p[4*i] = b.x; c2p[4*i+1] = b.y; c2p[4*i+2] = b.z; c2p[4*i+3] = b.w;
            float4 c = c4[i]; c2s[4*i] = c.x; c2s[4*i+1] = c.y; c2s[4*i+2] = c.z; c2s[4*i+3] = c.w;
            int4   d = q4[i]; q[4*i]   = d.x; q[4*i+1]   = d.y; q[4*i+2]   = d.z; q[4*i+3]   = d.w;
        }
    }

    // ---- order-independent base sums ----
    float s0 = 0.0f, t0 = 0.0f, s0r = 0.0f, t0r = 0.0f;
    #pragma unroll
    for (int k = 0; k < RR; ++k) {
        s0  = fmaf(c1s[k], l[k], s0);   t0  += l[k];
        s0r = fmaf(c2p[k], u[k], s0r);  t0r += u[k];
        UL[k][tid] = make_float2(u[k], l[k]);   // stash for the q-permuted right scan
    }

    // ---- LEFT endpoint: prefix-min of ratios, fully static (p1 order) ----
    float bn = s0, bd = t0, cs = s0, ct = t0;
    #pragma unroll
    for (int k = 0; k < RR; ++k) {
        float dd = u[k] - l[k];            // >= 0
        cs = fmaf(c1s[k], dd, cs);
        ct += dd;
        bool bet = (cs * bd < bn * ct);    // cs/ct < bn/bd  (denoms > 0)
        bn = bet ? cs : bn;
        bd = bet ? ct : bd;
    }
    float left = bn / bd;

    // ---- RIGHT endpoint: prefix-max in c2-sorted order via LDS permute ----
    bn = s0r; bd = t0r; cs = s0r; ct = t0r;
    #pragma unroll
    for (int k = 0; k < RR; ++k) {
        float2 ul = UL[q[k]][tid];         // q[k] uniform -> SGPR offset
        float dd = ul.y - ul.x;            // l - u <= 0
        cs = fmaf(c2s[k], dd, cs);
        ct += dd;
        bool bet = (cs * bd > bn * ct);
        bn = bet ? cs : bn;
        bd = bet ? ct : bd;
    }
    float right = bn / bd;

    out[gid] = 0.5f * (left + right);
}

extern "C" void kernel_launch(void* const* d_in, const int* in_sizes, int n_in,
                              void* d_out, int out_size, void* d_ws, size_t ws_size,
                              hipStream_t stream) {
    const float* x  = (const float*)d_in[0];
    const float* W  = (const float*)d_in[1];
    const float* c1 = (const float*)d_in[2];
    const float* c2 = (const float*)d_in[3];
    float* out = (float*)d_out;
    float* ws  = (float*)d_ws;
    const int n = out_size;   // 262144

    hipLaunchKernelGGL(prep_kernel, dim3(1), dim3(64), 0, stream, W, c1, c2, ws);

    const int blocks = (n + BLOCK - 1) / BLOCK;
    hipLaunchKernelGGL(t2fls_main, dim3(blocks), dim3(BLOCK), 0, stream,
                       x, ws, out, n);
}

// Round 4
// 70.163 us; speedup vs baseline: 1.0469x; 1.0469x over previous
//
#include <hip/hip_runtime.h>
#include <math.h>

#define RR 16
#define AA 8
#define BLOCK 256

typedef float v2f __attribute__((ext_vector_type(2)));

// ws float layout (rule rows permuted into c1-sorted order "k"):
//   [0..127]    mP   : m[k][a]
//   [128..383]  ivP  : interleaved (1/sigma_big, 1/sigma_small) per (k,a)
//   [384..399]  c1s  : c1 sorted ascending
//   [400..415]  c2p  : c2[p1[k]] (c2 coeffs in p1 order)
//   [416..431]  c2s  : c2 sorted ascending
//   [432..447]  qI   : (int) position in p1-order of rule p2[k]

__global__ void prep_kernel(const float* __restrict__ W,
                            const float* __restrict__ c1,
                            const float* __restrict__ c2,
                            float* __restrict__ ws) {
    int t = threadIdx.x;   // 64 threads, 1 block; 0..15 active
    if (t >= RR) return;

    float v1 = c1[t];
    int r1 = 0;                         // stable rank in c1
    #pragma unroll
    for (int j = 0; j < RR; ++j) {
        float vj = c1[j];
        r1 += (vj < v1) || (vj == v1 && j < t);
    }
    float v2 = c2[t];
    int r2 = 0;                         // stable rank in c2
    #pragma unroll
    for (int j = 0; j < RR; ++j) {
        float vj = c2[j];
        r2 += (vj < v2) || (vj == v2 && j < t);
    }

    #pragma unroll
    for (int a = 0; a < AA; ++a) {
        int o = t * AA + a;             // offsets = 8r + a ; m=W[o], s1=W[o+1], s2=W[o+2]
        float m  = W[o];
        float s1 = W[o + 1];
        float s2 = W[o + 2];
        ws[r1 * AA + a]                  = m;
        ws[128 + 2 * (r1 * AA + a)]      = 1.0f / fmaxf(s1, s2);  // big sigma -> UU
        ws[128 + 2 * (r1 * AA + a) + 1]  = 1.0f / fminf(s1, s2);  // small sigma -> LL
    }
    ws[384 + r1] = v1;
    ws[400 + r1] = v2;
    ws[416 + r2] = v2;
    ((int*)ws)[432 + r2] = r1;
}

__global__ __launch_bounds__(BLOCK) void t2fls_main(
    const float* __restrict__ x,    // N x 8
    const float* __restrict__ ws,   // prepped uniforms
    float* __restrict__ out,        // N
    int n)
{
    __shared__ float4 UL[RR / 2][BLOCK];   // 32 KiB; own-column access, no barrier

    const int tid = threadIdx.x;
    const int gid = blockIdx.x * BLOCK + tid;
    if (gid >= n) return;

    const float4* xp = (const float4*)(x + (size_t)gid * AA);
    const float4 xA = xp[0], xB = xp[1];
    const float xv[AA] = {xA.x, xA.y, xA.z, xA.w, xB.x, xB.y, xB.z, xB.w};

    const float4* m4  = (const float4*)(ws);
    const float4* iv4 = (const float4*)(ws + 128);  // 2 features per float4

    // ---- firing: per-rule d^2 sums via packed f32 (v_pk_fma_f32) ----
    float sb[RR], ss[RR];
    #pragma unroll
    for (int k = 0; k < RR; ++k) {
        v2f acc = {0.0f, 0.0f};
        #pragma unroll
        for (int h = 0; h < 2; ++h) {           // feature halves 0..3, 4..7
            float4 m = m4[2 * k + h];
            float4 pA = iv4[4 * k + 2 * h];     // features 2h*2+0,1 pairs
            float4 pB = iv4[4 * k + 2 * h + 1];
            float t0 = xv[4 * h]     - m.x;
            float t1 = xv[4 * h + 1] - m.y;
            float t2 = xv[4 * h + 2] - m.z;
            float t3 = xv[4 * h + 3] - m.w;
            v2f d;
            d = (v2f){t0, t0} * (v2f){pA.x, pA.y};  acc += d * d;
            d = (v2f){t1, t1} * (v2f){pA.z, pA.w};  acc += d * d;
            d = (v2f){t2, t2} * (v2f){pB.x, pB.y};  acc += d * d;
            d = (v2f){t3, t3} * (v2f){pB.z, pB.w};  acc += d * d;
        }
        sb[k] = acc.x;
        ss[k] = acc.y;
    }

    // ---- exact pow2 relative rescale (KM ratios scale-invariant) ----
    float smin = sb[0];
    #pragma unroll
    for (int k = 1; k < RR; ++k) smin = fminf(smin, sb[k]);

    const float K = 0.72134752044448f;  // 0.5 * log2(e)
    float u[RR], l[RR];
    #pragma unroll
    for (int k = 0; k < RR; ++k) {
        u[k] = __builtin_amdgcn_exp2f((smin - sb[k]) * K);
        l[k] = __builtin_amdgcn_exp2f((smin - ss[k]) * K);
    }

    // ---- uniform coefficient vectors ----
    float c1s[RR], c2p[RR], c2s[RR];
    int   q[RR];
    {
        const float4* a4 = (const float4*)(ws + 384);
        const float4* b4 = (const float4*)(ws + 400);
        const float4* c4 = (const float4*)(ws + 416);
        const int4*   q4 = (const int4*)((const int*)ws + 432);
        #pragma unroll
        for (int i = 0; i < 4; ++i) {
            float4 a = a4[i]; c1s[4*i] = a.x; c1s[4*i+1] = a.y; c1s[4*i+2] = a.z; c1s[4*i+3] = a.w;
            float4 b = b4[i]; c2p[4*i] = b.x; c2p[4*i+1] = b.y; c2p[4*i+2] = b.z; c2p[4*i+3] = b.w;
            float4 c = c4[i]; c2s[4*i] = c.x; c2s[4*i+1] = c.y; c2s[4*i+2] = c.z; c2s[4*i+3] = c.w;
            int4   d = q4[i]; q[4*i]   = d.x; q[4*i+1]   = d.y; q[4*i+2]   = d.z; q[4*i+3]   = d.w;
        }
    }

    // ---- base sums (packed) + LDS stash for the permuted right scan ----
    v2f vL = {0.0f, 0.0f};   // {s0, t0}
    v2f vR = {0.0f, 0.0f};   // {s0r, t0r}
    #pragma unroll
    for (int k = 0; k < RR; k += 2) {
        vL += (v2f){c1s[k],   1.0f} * (v2f){l[k],   l[k]};
        vL += (v2f){c1s[k+1], 1.0f} * (v2f){l[k+1], l[k+1]};
        vR += (v2f){c2p[k],   1.0f} * (v2f){u[k],   u[k]};
        vR += (v2f){c2p[k+1], 1.0f} * (v2f){u[k+1], u[k+1]};
        UL[k >> 1][tid] = make_float4(u[k], l[k], u[k+1], l[k+1]);
    }

    // ---- LEFT endpoint: prefix-min of ratios, fully static (p1 order) ----
    float bn = vL.x, bd = vL.y;
    v2f vcs = vL;
    #pragma unroll
    for (int k = 0; k < RR; ++k) {
        float dd = u[k] - l[k];                 // >= 0
        vcs += (v2f){c1s[k], 1.0f} * (v2f){dd, dd};
        bool bet = (vcs.x * bd < bn * vcs.y);   // cs/ct < bn/bd (denoms > 0)
        bn = bet ? vcs.x : bn;
        bd = bet ? vcs.y : bd;
    }
    float left = bn / bd;

    // ---- RIGHT endpoint: prefix-max in c2-sorted order via LDS permute ----
    bn = vR.x; bd = vR.y;
    vcs = vR;
    #pragma unroll
    for (int k = 0; k < RR; ++k) {
        int p = q[k];                           // uniform
        const float2* row = (const float2*)&UL[p >> 1][tid];
        float2 ul = row ? ((const float2*)&UL[p >> 1][tid])[p & 1] : make_float2(0.f, 0.f);
        float dd = ul.y - ul.x;                 // l - u <= 0
        vcs += (v2f){c2s[k], 1.0f} * (v2f){dd, dd};
        bool bet = (vcs.x * bd > bn * vcs.y);
        bn = bet ? vcs.x : bn;
        bd = bet ? vcs.y : bd;
    }
    float right = bn / bd;

    out[gid] = 0.5f * (left + right);
}

extern "C" void kernel_launch(void* const* d_in, const int* in_sizes, int n_in,
                              void* d_out, int out_size, void* d_ws, size_t ws_size,
                              hipStream_t stream) {
    const float* x  = (const float*)d_in[0];
    const float* W  = (const float*)d_in[1];
    const float* c1 = (const float*)d_in[2];
    const float* c2 = (const float*)d_in[3];
    float* out = (float*)d_out;
    float* ws  = (float*)d_ws;
    const int n = out_size;   // 262144

    hipLaunchKernelGGL(prep_kernel, dim3(1), dim3(64), 0, stream, W, c1, c2, ws);

    const int blocks = (n + BLOCK - 1) / BLOCK;
    hipLaunchKernelGGL(t2fls_main, dim3(blocks), dim3(BLOCK), 0, stream,
                       x, ws, out, n);
}